// Round 3
// baseline (566.278 us; speedup 1.0000x reference)
//
#include <hip/hip_runtime.h>
#include <hip/hip_bf16.h>

typedef __bf16 bf16x8 __attribute__((ext_vector_type(8)));
typedef float  f32x4  __attribute__((ext_vector_type(4)));

// ---------- helpers ----------
static __device__ __forceinline__ unsigned short f2bf(float f) {
  unsigned int u = __float_as_uint(f);
  u += 0x7FFFu + ((u >> 16) & 1u);   // round-to-nearest-even
  return (unsigned short)(u >> 16);
}

static __device__ __forceinline__ void gl_lds16(const void* g, void* l) {
  __builtin_amdgcn_global_load_lds(
      (const __attribute__((address_space(1))) void*)g,
      (__attribute__((address_space(3))) void*)l,
      16, 0, 0);
}

// ---------- cast x: f32 -> bf16 ----------
__global__ __launch_bounds__(256) void cast_f32_bf16(
    const float* __restrict__ in, unsigned short* __restrict__ out, int n) {
  int i = (blockIdx.x * 256 + threadIdx.x) * 4;
  const int stride = gridDim.x * 256 * 4;
  for (; i < n; i += stride) {
    float4 f = *(const float4*)(in + i);
    ushort4 o;
    o.x = f2bf(f.x); o.y = f2bf(f.y); o.z = f2bf(f.z); o.w = f2bf(f.w);
    *(ushort4*)(out + i) = o;
  }
}

// ---------- transpose-cast W (1024x1024): wt[n][k] = w[k][n], f32 -> bf16 ----------
__global__ __launch_bounds__(256) void transpose_cast_w(
    const float* __restrict__ w, unsigned short* __restrict__ wt) {
  __shared__ float tile[16][17];
  const int tx = threadIdx.x & 15, ty = threadIdx.x >> 4;
  const int bx = blockIdx.x * 16, by = blockIdx.y * 16;
  tile[ty][tx] = w[(size_t)(by + ty) * 1024 + bx + tx];
  __syncthreads();
  wt[(size_t)(bx + ty) * 1024 + by + tx] = f2bf(tile[tx][ty]);
}

// ---------- 256x256-tile bf16 MFMA GEMM, BK=32, 4-slot LDS ring, 8 waves ----------
// B given transposed ([N][K]). XCD-locality remap: d2 -> (ty=d2%gy, tx=d2/gy);
// all tiles sharing an A row-panel have equal d2%8 -> same XCD.
// LDS layout per slot (32 KB): A region 16 KB as [kq 0..3][row 0..255][16B],
// B region 16 KB same with N-rows. Conflict-free ds_read_b128 by construction;
// global_load_lds dest is linear (wave-uniform base + lane*16).
// Schedule per K-tile t (uniform counted vmcnt, stages never drained):
//   vmcnt(8) ; s_barrier ; 12x ds_read_b128 ; stage t+3 ; setprio1 ; 32 MFMA ; setprio0 ; s_barrier
// Slot (t+3)&3 was last read in phase t-1 (reads retired before that phase's
// end barrier via compiler lgkmcnt), so the phase-t stage-issue is safe.
// MODE 2: C f32 [z*cstride + row*ldc + col]
// MODE 3: fused-QKV split write (Cv = qb base; kb = +16Mi elems, vt = +32Mi):
//   col<1024 -> q bf16 [row][col]; col<2048 -> k bf16 [row][col-1024];
//   col>=2048 -> vT bf16 [(b*1024+col-2048)*2048 + s], b=row>>11, s=row&2047
template <int MODE>
__global__ __launch_bounds__(512, 2) void gemm256(
    const unsigned short* __restrict__ A, int lda, size_t astride,
    const unsigned short* __restrict__ B, int ldb, size_t bstride,
    int K, void* __restrict__ Cv, int ldc, size_t cstride) {
  __shared__ __align__(16) unsigned char lds[131072];  // 4 slots x (A 16KB | B 16KB)

  const unsigned d2 = blockIdx.x + gridDim.x * blockIdx.y;
  const unsigned ty = d2 % gridDim.y;
  const unsigned tx = d2 / gridDim.y;
  const int bm0 = ty * 256;
  const int bn0 = tx * 256;
  A += (size_t)blockIdx.z * astride;
  B += (size_t)blockIdx.z * bstride;

  const int tid = threadIdx.x;
  const int wid = tid >> 6, lane = tid & 63;
  const int wr = wid >> 2, wc = wid & 3;        // wave grid 2(M) x 4(N)
  const int l15 = lane & 15, kq = lane >> 4;

  // staging: 16B chunk c = j*512 + wid*64 + lane ; kq_g = c>>8 ; row = c&255
  const int srow = ((wid & 3) << 6) + lane;     // row for both j=0,1
  const int skq0 = wid >> 2;                    // j=0 -> kq_g = skq0 ; j=1 -> skq0+2
  const size_t aoff0 = (size_t)(bm0 + srow) * lda + skq0 * 8;
  const size_t aoff1 = aoff0 + 16;              // +2 K-groups = +16 elems
  const size_t boff0 = (size_t)(bn0 + srow) * ldb + skq0 * 8;
  const size_t boff1 = boff0 + 16;
  const int ldst0 = (wid * 64) * 16;            // wave-uniform LDS byte offsets
  const int ldst1 = (512 + wid * 64) * 16;

#define STAGE(t) do { \
    unsigned char* sA_ = lds + ((t) & 3) * 32768; \
    unsigned char* sB_ = sA_ + 16384; \
    const size_t kc_ = (size_t)(t) * 32; \
    gl_lds16(A + aoff0 + kc_, sA_ + ldst0); \
    gl_lds16(A + aoff1 + kc_, sA_ + ldst1); \
    gl_lds16(B + boff0 + kc_, sB_ + ldst0); \
    gl_lds16(B + boff1 + kc_, sB_ + ldst1); \
  } while (0)

  f32x4 acc[8][4] = {};
  const int nkt = K >> 5;

  STAGE(0);
  if (nkt > 1) STAGE(1);
  if (nkt > 2) STAGE(2);

  for (int t = 0; t < nkt; ++t) {
    const int rem = nkt - 1 - t;
    if (rem >= 2)      asm volatile("s_waitcnt vmcnt(8)" ::: "memory");
    else if (rem == 1) asm volatile("s_waitcnt vmcnt(4)" ::: "memory");
    else               asm volatile("s_waitcnt vmcnt(0)" ::: "memory");
    __builtin_amdgcn_s_barrier();   // now every wave's tile-t stage has landed

    const unsigned char* sA = lds + (t & 3) * 32768;
    const unsigned char* sB = sA + 16384;
    bf16x8 af[8], bg[4];
#pragma unroll
    for (int mi = 0; mi < 8; ++mi)
      af[mi] = *(const bf16x8*)(sA + kq * 4096 + (wr * 128 + mi * 16 + l15) * 16);
#pragma unroll
    for (int ni = 0; ni < 4; ++ni)
      bg[ni] = *(const bf16x8*)(sB + kq * 4096 + (wc * 64 + ni * 16 + l15) * 16);

    if (t + 3 < nkt) STAGE(t + 3);  // 3 tiles in flight across the barrier

    __builtin_amdgcn_s_setprio(1);
#pragma unroll
    for (int mi = 0; mi < 8; ++mi)
#pragma unroll
      for (int ni = 0; ni < 4; ++ni)
        acc[mi][ni] = __builtin_amdgcn_mfma_f32_16x16x32_bf16(af[mi], bg[ni], acc[mi][ni], 0, 0, 0);
    __builtin_amdgcn_s_setprio(0);
    __builtin_amdgcn_s_barrier();   // phase end: reads of slot t&3 retired
  }
#undef STAGE

  // epilogue: C/D layout col = lane&15, row = (lane>>4)*4 + reg  [verified m89/m91]
#pragma unroll
  for (int mi = 0; mi < 8; ++mi) {
#pragma unroll
    for (int ni = 0; ni < 4; ++ni) {
#pragma unroll
      for (int r = 0; r < 4; ++r) {
        const int row = bm0 + wr * 128 + mi * 16 + kq * 4 + r;
        const int col = bn0 + wc * 64 + ni * 16 + l15;
        const float v = acc[mi][ni][r];
        if constexpr (MODE == 2) {
          ((float*)Cv)[(size_t)blockIdx.z * cstride + (size_t)row * ldc + col] = v;
        } else {  // MODE 3: fused QKV
          unsigned short* q = (unsigned short*)Cv;
          if (col < 1024) {
            q[(size_t)row * 1024 + col] = f2bf(v);
          } else if (col < 2048) {
            q[16777216u + (size_t)row * 1024 + (col - 1024)] = f2bf(v);
          } else {
            const int b = row >> 11, s = row & 2047;
            q[33554432u + ((size_t)(b * 1024 + (col - 2048))) * 2048 + s] = f2bf(v);
          }
        }
      }
    }
  }
}

// ---------- row softmax over 2048 fp32 scores; writes bf16 P in-place (ld 4096) ----------
__global__ __launch_bounds__(256) void softmax_rows(float* __restrict__ scores) {
  float* base = scores + (size_t)blockIdx.y * 4194304 + (size_t)blockIdx.x * 2048;
  const int tid = threadIdx.x;
  const int wid = tid >> 6, lane = tid & 63;

  float v[8];
  float m = -1e30f;
#pragma unroll
  for (int i = 0; i < 8; ++i) {
    v[i] = base[tid + i * 256] * 0.03125f;  // 1/sqrt(1024)
    m = fmaxf(m, v[i]);
  }
  for (int off = 32; off; off >>= 1) m = fmaxf(m, __shfl_xor(m, off));
  __shared__ float redm[4], reds[4];
  if (lane == 0) redm[wid] = m;
  __syncthreads();            // all global reads of this row complete before here
  m = fmaxf(fmaxf(redm[0], redm[1]), fmaxf(redm[2], redm[3]));

  float s = 0.f;
#pragma unroll
  for (int i = 0; i < 8; ++i) { v[i] = expf(v[i] - m); s += v[i]; }
  for (int off = 32; off; off >>= 1) s += __shfl_xor(s, off);
  if (lane == 0) reds[wid] = s;
  __syncthreads();
  s = reds[0] + reds[1] + reds[2] + reds[3];
  const float inv = 1.0f / s;

  unsigned short* p = (unsigned short*)base;  // bf16 P, ld 4096, in-place (safe: writes after barrier)
#pragma unroll
  for (int i = 0; i < 8; ++i) p[tid + i * 256] = f2bf(v[i] * inv);
}

// ---------- launch ----------
extern "C" void kernel_launch(void* const* d_in, const int* in_sizes, int n_in,
                              void* d_out, int out_size, void* d_ws, size_t ws_size,
                              hipStream_t stream) {
  const float* x  = (const float*)d_in[0];
  const float* Wq = (const float*)d_in[1];
  const float* Wk = (const float*)d_in[2];
  const float* Wv = (const float*)d_in[3];
  float* out = (float*)d_out;
  char* ws = (char*)d_ws;

  // workspace layout (bytes)
  unsigned short* xb     = (unsigned short*)ws;                  // 33.5 MB
  unsigned short* wt_all = (unsigned short*)(ws + 33554432);     // 6 MB: WqT|WkT|WvT [3072][1024]
  unsigned short* qb     = (unsigned short*)(ws + 39845888);     // 33.5 MB
  unsigned short* kb     = qb + 16777216;                        // 33.5 MB
  unsigned short* vt     = kb + 16777216;                        // 33.5 MB (vT: [b*1024+e][s])
  const size_t off_scores = 140509184;                           // end of vt

  // scores scratch: 16 MiB per batch (2048 x 2048 fp32). Batch G at a time.
  int G; float* scores;
  if (ws_size >= off_scores + 8ull * 16777216) {
    G = 8; scores = (float*)(ws + off_scores);
  } else if (ws_size >= off_scores + 16777216) {
    size_t g = (ws_size - off_scores) / 16777216; G = (int)(g > 8 ? 8 : g);
    scores = (float*)(ws + off_scores);
  } else {
    G = 2; scores = (float*)ws;  // reuse xb region; xb dead after QKV
  }

  cast_f32_bf16<<<2048, 256, 0, stream>>>(x, xb, 16384 * 1024);
  transpose_cast_w<<<dim3(64, 64), 256, 0, stream>>>(Wq, wt_all);
  transpose_cast_w<<<dim3(64, 64), 256, 0, stream>>>(Wk, wt_all + 1048576);
  transpose_cast_w<<<dim3(64, 64), 256, 0, stream>>>(Wv, wt_all + 2097152);

  // fused QKV projection: M=16384, N=3072, K=1024 -> grid 12 x 64
  gemm256<3><<<dim3(12, 64), 512, 0, stream>>>(xb, 1024, 0, wt_all, 1024, 0,
                                               1024, qb, 0, 0);

  for (int b0 = 0; b0 < 8; b0 += G) {
    const int g = (8 - b0) < G ? (8 - b0) : G;
    const size_t so = (size_t)b0 * 2097152;  // q/k/v/out batch offset (elems)
    // scores = q·k^T (fp32): M=N=2048, K=1024, batched over z
    gemm256<2><<<dim3(8, 8, g), 512, 0, stream>>>(
        qb + so, 1024, 2097152, kb + so, 1024, 2097152, 1024,
        scores, 2048, 4194304);
    // softmax rows (applies 1/32 scale), P bf16 in-place at ld 4096
    softmax_rows<<<dim3(2048, g), 256, 0, stream>>>(scores);
    // out = P·v : A=P (lda 4096 ushort), B^T = vT_b [1024][2048], M=2048, N=1024, K=2048
    gemm256<2><<<dim3(4, 8, g), 512, 0, stream>>>(
        (const unsigned short*)scores, 4096, 8388608,
        vt + so, 2048, 2097152, 2048,
        out + so, 1024, 2097152);
  }
}